// Round 2
// baseline (457.012 us; speedup 1.0000x reference)
//
#include <hip/hip_runtime.h>

#define NPTS 131072
#define NCEN 128

// Mahalanobis quadratic form, numpy-order (mul then add, explicit _rn ops so
// pass-1 and pass-2 evaluations are bit-identical: no fma contraction).
// C layout per center: inv_cov A[9] row-major, then center xyz at [9..11].
__device__ __forceinline__ float qeval(const float* __restrict__ C,
                                       float px, float py, float pz) {
    float dx = __fsub_rn(px, C[9]);
    float dy = __fsub_rn(py, C[10]);
    float dz = __fsub_rn(pz, C[11]);
    float t0 = __fadd_rn(__fadd_rn(__fmul_rn(dx, C[0]), __fmul_rn(dy, C[3])), __fmul_rn(dz, C[6]));
    float t1 = __fadd_rn(__fadd_rn(__fmul_rn(dx, C[1]), __fmul_rn(dy, C[4])), __fmul_rn(dz, C[7]));
    float t2 = __fadd_rn(__fadd_rn(__fmul_rn(dx, C[2]), __fmul_rn(dy, C[5])), __fmul_rn(dz, C[8]));
    return __fadd_rn(__fadd_rn(__fmul_rn(t0, dx), __fmul_rn(t1, dy)), __fmul_rn(t2, dz));
}

// ---------- kernel 1: per-center inv_cov (R diag(1/(|r|+eps)) R^T) + bbox pen ----------
__global__ void k_precompute(const float* __restrict__ centers,
                             const float* __restrict__ radii,
                             const float* __restrict__ rots,
                             float* __restrict__ ws) {
    int n = threadIdx.x;
    if (n >= NCEN) return;
    float c0 = centers[3 * n + 0];
    float c1 = centers[3 * n + 1];
    float c2 = centers[3 * n + 2];
    float d0 = 1.0f / (fabsf(radii[3 * n + 0]) + 1e-8f);
    float d1 = 1.0f / (fabsf(radii[3 * n + 1]) + 1e-8f);
    float d2 = 1.0f / (fabsf(radii[3 * n + 2]) + 1e-8f);
    float a0 = rots[3 * n + 0];
    float a1 = rots[3 * n + 1];
    float a2 = rots[3 * n + 2];
    float cx = cosf(a0), cy = cosf(a1), cz = cosf(a2);
    float sx = sinf(a0), sy = sinf(a1), sz = sinf(a2);
    float R[9];
    R[0] = __fmul_rn(cz, cy);
    R[1] = __fsub_rn(__fmul_rn(__fmul_rn(cz, sy), sx), __fmul_rn(sz, cx));
    R[2] = __fadd_rn(__fmul_rn(__fmul_rn(cz, sy), cx), __fmul_rn(sz, sx));
    R[3] = __fmul_rn(sz, cy);
    R[4] = __fadd_rn(__fmul_rn(__fmul_rn(sz, sy), sx), __fmul_rn(cz, cx));
    R[5] = __fsub_rn(__fmul_rn(__fmul_rn(sz, sy), cx), __fmul_rn(cz, sx));
    R[6] = -sy;
    R[7] = __fmul_rn(cy, sx);
    R[8] = __fmul_rn(cy, cx);
    float T[9];
    T[0] = __fmul_rn(R[0], d0); T[1] = __fmul_rn(R[1], d1); T[2] = __fmul_rn(R[2], d2);
    T[3] = __fmul_rn(R[3], d0); T[4] = __fmul_rn(R[4], d1); T[5] = __fmul_rn(R[5], d2);
    T[6] = __fmul_rn(R[6], d0); T[7] = __fmul_rn(R[7], d1); T[8] = __fmul_rn(R[8], d2);
    float* W = ws + n * 12;
#pragma unroll
    for (int a = 0; a < 3; ++a)
#pragma unroll
        for (int c = 0; c < 3; ++c)
            W[3 * a + c] = __fadd_rn(__fadd_rn(__fmul_rn(T[3 * a + 0], R[3 * c + 0]),
                                               __fmul_rn(T[3 * a + 1], R[3 * c + 1])),
                                     __fmul_rn(T[3 * a + 2], R[3 * c + 2]));
    W[9] = c0; W[10] = c1; W[11] = c2;
    float bb = fmaxf(c0 - 0.5f, 0.f) + fmaxf(-0.5f - c0, 0.f)
             + fmaxf(c1 - 0.5f, 0.f) + fmaxf(-0.5f - c1, 0.f)
             + fmaxf(c2 - 0.5f, 0.f) + fmaxf(-0.5f - c2, 0.f);
    atomicAdd(ws + NCEN * 12 + 1, bb);
}

// ---------- kernel 2: main fused pass (weights, top-16 select, masked-gather blend) ----------
// Pre-filter bound: 5*exp(-12.5/2)=0.00965<0.01 and w>=0.01 => q<=12.430, so the
// q<=12.5 pre-filter never drops a maskable center. If >=16 centers pass it,
// top[15] is the exact 16th-smallest q; otherwise qc=12.5 covers every maskable
// center and the w>=0.01 mask trims exactly. Selection thus matches
// top_k(w,16) followed by w>=WEIGHT_MIN (up to measure-zero exact float ties).
__global__ __launch_bounds__(256) void k_main(
        const float* __restrict__ wxyz,
        const float* __restrict__ dists,
        const float4* __restrict__ rgbs,
        const float* __restrict__ ws,
        float4* __restrict__ outv,
        float* __restrict__ pen_out) {
    int p = blockIdx.x * 256 + threadIdx.x;
    float px = wxyz[3 * p + 0];
    float py = wxyz[3 * p + 1];
    float pz = wxyz[3 * p + 2];
    float dist = dists[p];

    float top[16];
#pragma unroll
    for (int i = 0; i < 16; ++i) top[i] = 3.0e38f;
    float pen = 0.f;

    // pass 1: sparsity penalty + 16-smallest-q tracking (branch-free sorted insert)
#pragma unroll 2
    for (int n = 0; n < NCEN; ++n) {
        float q = qeval(ws + n * 12, px, py, pz);
        if (q <= 12.5f) {
            float w = __fmul_rn(5.0f, expf(__fmul_rn(-0.5f, q)));
            pen = __fadd_rn(pen, fmaxf(__fsub_rn(w, 0.01f), 0.f));
#pragma unroll
            for (int j = 15; j >= 1; --j)
                top[j] = fminf(top[j], fmaxf(q, top[j - 1]));
            top[0] = fminf(top[0], q);
        }
    }
    float qc = fminf(top[15], 12.5f);

    // pass 2: recompute q (bit-identical); rgbs load is exec-mask-predicated so
    // only selected (<=16 of 128) 16B entries are fetched (hardware gather).
    float wsum = 0.f, s0 = 0.f, s1 = 0.f, s2 = 0.f, s3 = 0.f;
#pragma unroll 4
    for (int n = 0; n < NCEN; ++n) {
        float q = qeval(ws + n * 12, px, py, pz);
        if (q <= qc) {
            float w = __fmul_rn(5.0f, expf(__fmul_rn(-0.5f, q)));
            if (w >= 0.01f) {
                float4 rv = rgbs[(size_t)n * NPTS + p];
                float al = __fsub_rn(1.0f, expf(-__fmul_rn(fmaxf(rv.w, 0.f), dist)));
                wsum += w;
                s0 = __fmaf_rn(w, rv.x, s0);
                s1 = __fmaf_rn(w, rv.y, s1);
                s2 = __fmaf_rn(w, rv.z, s2);
                s3 = __fmaf_rn(w, al, s3);
            }
        }
    }
    float inv = 1.0f / (wsum + 1e-7f);
    float4 o;
    o.x = s0 * inv; o.y = s1 * inv; o.z = s2 * inv; o.w = s3 * inv;
    outv[p] = o;

    // penalty reduction: wave shuffle, one atomic per wave
    float v = pen;
#pragma unroll
    for (int off = 32; off > 0; off >>= 1) v += __shfl_down(v, off);
    if ((threadIdx.x & 63) == 0) atomicAdd(pen_out, v);
}

// ---------- kernel 3: finalize scalar penalty ----------
__global__ void k_finalize(const float* __restrict__ ws,
                           float* __restrict__ out) {
    if (threadIdx.x == 0) {
        float m = ws[NCEN * 12] / (float)NPTS;       // mean over points
        out[NPTS * 4] = __fadd_rn(__fmul_rn(0.001f, m), ws[NCEN * 12 + 1]);
    }
}

extern "C" void kernel_launch(void* const* d_in, const int* in_sizes, int n_in,
                              void* d_out, int out_size, void* d_ws, size_t ws_size,
                              hipStream_t stream) {
    const float*  wxyz  = (const float*)d_in[0];
    const float*  cen   = (const float*)d_in[1];
    const float*  rad   = (const float*)d_in[2];
    const float*  rot   = (const float*)d_in[3];
    const float4* rgbs  = (const float4*)d_in[4];
    const float*  dists = (const float*)d_in[5];
    float* ws = (float*)d_ws;

    // zero the two accumulators (pen sum, bbox sum); ws is re-poisoned each call
    hipMemsetAsync(ws + NCEN * 12, 0, 2 * sizeof(float), stream);
    hipLaunchKernelGGL(k_precompute, dim3(1), dim3(128), 0, stream, cen, rad, rot, ws);
    hipLaunchKernelGGL(k_main, dim3(NPTS / 256), dim3(256), 0, stream,
                       wxyz, dists, rgbs, ws, (float4*)d_out, ws + NCEN * 12);
    hipLaunchKernelGGL(k_finalize, dim3(1), dim3(64), 0, stream, ws, (float*)d_out);
}

// Round 3
// 444.453 us; speedup vs baseline: 1.0283x; 1.0283x over previous
//
#include <hip/hip_runtime.h>

#define NPTS 131072
#define NCEN 128

// Mahalanobis quadratic form, numpy-order (mul then add, explicit _rn ops: no
// fma contraction, stays close to the np reference bit-for-bit).
// C layout per center: inv_cov A[9] row-major, then center xyz at [9..11].
__device__ __forceinline__ float qeval(const float* C,
                                       float px, float py, float pz) {
    float dx = __fsub_rn(px, C[9]);
    float dy = __fsub_rn(py, C[10]);
    float dz = __fsub_rn(pz, C[11]);
    float t0 = __fadd_rn(__fadd_rn(__fmul_rn(dx, C[0]), __fmul_rn(dy, C[3])), __fmul_rn(dz, C[6]));
    float t1 = __fadd_rn(__fadd_rn(__fmul_rn(dx, C[1]), __fmul_rn(dy, C[4])), __fmul_rn(dz, C[7]));
    float t2 = __fadd_rn(__fadd_rn(__fmul_rn(dx, C[2]), __fmul_rn(dy, C[5])), __fmul_rn(dz, C[8]));
    return __fadd_rn(__fadd_rn(__fmul_rn(t0, dx), __fmul_rn(t1, dy)), __fmul_rn(t2, dz));
}

// ---------- kernel 1: zero accumulators + per-center inv_cov + bbox pen ----------
__global__ void k_precompute(const float* __restrict__ centers,
                             const float* __restrict__ radii,
                             const float* __restrict__ rots,
                             float* __restrict__ ws) {
    int n = threadIdx.x;
    if (n < 2) ws[NCEN * 12 + n] = 0.f;   // pen accum, bbox accum
    __syncthreads();                      // single block: safe ordering vs atomics
    if (n >= NCEN) return;
    float c0 = centers[3 * n + 0];
    float c1 = centers[3 * n + 1];
    float c2 = centers[3 * n + 2];
    float d0 = 1.0f / (fabsf(radii[3 * n + 0]) + 1e-8f);
    float d1 = 1.0f / (fabsf(radii[3 * n + 1]) + 1e-8f);
    float d2 = 1.0f / (fabsf(radii[3 * n + 2]) + 1e-8f);
    float a0 = rots[3 * n + 0];
    float a1 = rots[3 * n + 1];
    float a2 = rots[3 * n + 2];
    float cx = cosf(a0), cy = cosf(a1), cz = cosf(a2);
    float sx = sinf(a0), sy = sinf(a1), sz = sinf(a2);
    float R[9];
    R[0] = __fmul_rn(cz, cy);
    R[1] = __fsub_rn(__fmul_rn(__fmul_rn(cz, sy), sx), __fmul_rn(sz, cx));
    R[2] = __fadd_rn(__fmul_rn(__fmul_rn(cz, sy), cx), __fmul_rn(sz, sx));
    R[3] = __fmul_rn(sz, cy);
    R[4] = __fadd_rn(__fmul_rn(__fmul_rn(sz, sy), sx), __fmul_rn(cz, cx));
    R[5] = __fsub_rn(__fmul_rn(__fmul_rn(sz, sy), cx), __fmul_rn(cz, sx));
    R[6] = -sy;
    R[7] = __fmul_rn(cy, sx);
    R[8] = __fmul_rn(cy, cx);
    float T[9];
    T[0] = __fmul_rn(R[0], d0); T[1] = __fmul_rn(R[1], d1); T[2] = __fmul_rn(R[2], d2);
    T[3] = __fmul_rn(R[3], d0); T[4] = __fmul_rn(R[4], d1); T[5] = __fmul_rn(R[5], d2);
    T[6] = __fmul_rn(R[6], d0); T[7] = __fmul_rn(R[7], d1); T[8] = __fmul_rn(R[8], d2);
    float* W = ws + n * 12;
#pragma unroll
    for (int a = 0; a < 3; ++a)
#pragma unroll
        for (int c = 0; c < 3; ++c)
            W[3 * a + c] = __fadd_rn(__fadd_rn(__fmul_rn(T[3 * a + 0], R[3 * c + 0]),
                                               __fmul_rn(T[3 * a + 1], R[3 * c + 1])),
                                     __fmul_rn(T[3 * a + 2], R[3 * c + 2]));
    W[9] = c0; W[10] = c1; W[11] = c2;
    float bb = fmaxf(c0 - 0.5f, 0.f) + fmaxf(-0.5f - c0, 0.f)
             + fmaxf(c1 - 0.5f, 0.f) + fmaxf(-0.5f - c1, 0.f)
             + fmaxf(c2 - 0.5f, 0.f) + fmaxf(-0.5f - c2, 0.f);
    atomicAdd(ws + NCEN * 12 + 1, bb);
}

// ---------- kernel 2: 4 threads/point; branchless top-16; butterfly merge ----------
// Selection logic: top[] network inserts ALL q (inserting q>12.5 can never evict
// a true top-16 member); qc = min(16th smallest q, 12.5). 5*exp(-12.5/2)=0.00965
// < 0.01, so {q<=qc} + exact w>=0.01 mask reproduces top_k(w,16)+threshold.
// Pen is branchless-exact: relu(w-0.01)=0 whenever q>12.43.
__global__ __launch_bounds__(256, 4) void k_main(
        const float* __restrict__ wxyz,
        const float* __restrict__ dists,
        const float4* __restrict__ rgbs,
        const float* __restrict__ ws,
        float* __restrict__ out,
        float* __restrict__ pen_out) {
    __shared__ float sws[NCEN * 12];
    int tid = threadIdx.x;
#pragma unroll
    for (int i = tid; i < NCEN * 12; i += 256) sws[i] = ws[i];
    __syncthreads();

    int gid = blockIdx.x * 256 + tid;
    int p = gid >> 2;          // point index
    int slice = gid & 3;       // center slice: n = 4j + slice (strided -> LDS conflict-free)
    float px = wxyz[3 * p + 0];
    float py = wxyz[3 * p + 1];
    float pz = wxyz[3 * p + 2];
    float dist = dists[p];

    float q[32];
    float top[16];
#pragma unroll
    for (int i = 0; i < 16; ++i) top[i] = 3.0e38f;
    float pen = 0.f;

    // pass 1: q for my 32 centers (cached in regs), pen, sorted top-16 insert
#pragma unroll
    for (int j = 0; j < 32; ++j) {
        int n = 4 * j + slice;
        float qq = qeval(&sws[n * 12], px, py, pz);
        q[j] = qq;
        float w = __fmul_rn(5.0f, expf(__fmul_rn(-0.5f, qq)));
        pen = __fadd_rn(pen, fmaxf(__fsub_rn(w, 0.01f), 0.f));
#pragma unroll
        for (int jj = 15; jj >= 1; --jj)
            top[jj] = fminf(top[jj], fmaxf(qq, top[jj - 1]));
        top[0] = fminf(top[0], qq);
    }

    // merge level 1 (lanes xor 1): lowest-16 of union, then bitonic cleanup
    float m[16];
#pragma unroll
    for (int i = 0; i < 16; ++i) {
        float b = __shfl_xor(top[15 - i], 1);
        m[i] = fminf(top[i], b);
    }
#pragma unroll
    for (int d = 8; d >= 1; d >>= 1) {
#pragma unroll
        for (int i = 0; i < 16; ++i) {
            if ((i & d) == 0) {
                float lo = fminf(m[i], m[i + d]);
                float hi = fmaxf(m[i], m[i + d]);
                m[i] = lo; m[i + d] = hi;
            }
        }
    }
    // merge level 2 (lanes xor 2): 16th smallest = max of pairwise mins
    float qc = -3.0e38f;
#pragma unroll
    for (int i = 0; i < 16; ++i) {
        float b = __shfl_xor(m[15 - i], 2);
        qc = fmaxf(qc, fminf(m[i], b));
    }
    qc = fminf(qc, 12.5f);

    // pass 2: cached q, predicated gather + blend of selected centers
    float wsum = 0.f, s0 = 0.f, s1 = 0.f, s2 = 0.f, s3 = 0.f;
#pragma unroll
    for (int j = 0; j < 32; ++j) {
        if (q[j] <= qc) {
            float w = __fmul_rn(5.0f, expf(__fmul_rn(-0.5f, q[j])));
            if (w >= 0.01f) {
                int n = 4 * j + slice;
                float4 rv = rgbs[(size_t)n * NPTS + p];
                float al = __fsub_rn(1.0f, expf(-__fmul_rn(fmaxf(rv.w, 0.f), dist)));
                wsum += w;
                s0 = __fmaf_rn(w, rv.x, s0);
                s1 = __fmaf_rn(w, rv.y, s1);
                s2 = __fmaf_rn(w, rv.z, s2);
                s3 = __fmaf_rn(w, al, s3);
            }
        }
    }
    // allreduce blend partials across the 4 lanes of this point
#pragma unroll
    for (int off = 1; off <= 2; off <<= 1) {
        wsum += __shfl_xor(wsum, off);
        s0   += __shfl_xor(s0, off);
        s1   += __shfl_xor(s1, off);
        s2   += __shfl_xor(s2, off);
        s3   += __shfl_xor(s3, off);
    }
    float inv = 1.0f / (wsum + 1e-7f);
    float val = (slice == 0) ? s0 : (slice == 1) ? s1 : (slice == 2) ? s2 : s3;
    out[gid] = val * inv;   // gid == p*4 + slice: fully coalesced

    // penalty reduction: wave shuffle, one atomic per wave
    float v = pen;
#pragma unroll
    for (int off = 32; off > 0; off >>= 1) v += __shfl_down(v, off);
    if ((tid & 63) == 0) atomicAdd(pen_out, v);
}

// ---------- kernel 3: finalize scalar penalty ----------
__global__ void k_finalize(const float* __restrict__ ws,
                           float* __restrict__ out) {
    if (threadIdx.x == 0) {
        float m = ws[NCEN * 12] / (float)NPTS;       // mean over points
        out[NPTS * 4] = __fadd_rn(__fmul_rn(0.001f, m), ws[NCEN * 12 + 1]);
    }
}

extern "C" void kernel_launch(void* const* d_in, const int* in_sizes, int n_in,
                              void* d_out, int out_size, void* d_ws, size_t ws_size,
                              hipStream_t stream) {
    const float*  wxyz  = (const float*)d_in[0];
    const float*  cen   = (const float*)d_in[1];
    const float*  rad   = (const float*)d_in[2];
    const float*  rot   = (const float*)d_in[3];
    const float4* rgbs  = (const float4*)d_in[4];
    const float*  dists = (const float*)d_in[5];
    float* ws = (float*)d_ws;

    hipLaunchKernelGGL(k_precompute, dim3(1), dim3(128), 0, stream, cen, rad, rot, ws);
    hipLaunchKernelGGL(k_main, dim3(4 * NPTS / 256), dim3(256), 0, stream,
                       wxyz, dists, rgbs, ws, (float*)d_out, ws + NCEN * 12);
    hipLaunchKernelGGL(k_finalize, dim3(1), dim3(64), 0, stream, ws, (float*)d_out);
}